// Round 1
// baseline (1455.652 us; speedup 1.0000x reference)
//
#include <hip/hip_runtime.h>

// Problem constants (match reference: B=32, TQ=TK=1024, D=64)
constexpr int TQn = 1024, TKn = 1024, Dn = 64;
constexpr int BB = 8;          // batches per block
constexpr int BQ = 8;          // queries per block
constexpr int KT = 128;        // k-tile
constexpr int NT = TKn / KT;   // 8 tiles
constexpr int QSTR = 68;       // lQ row stride (floats), padded, 16B-aligned rows
constexpr int SSTR = KT + 4;   // lS row stride (floats), padded, 16B-aligned rows

__global__ __launch_bounds__(256, 2)
void attn_rpr(const float* __restrict__ Qg, const float* __restrict__ Kg,
              const float* __restrict__ Vg, const float* __restrict__ PKg,
              const float* __restrict__ PVg, const int* __restrict__ VLg,
              float* __restrict__ Og) {
  __shared__ __align__(16) float lQ[64 * QSTR];   // 17408 B
  __shared__ __align__(16) float lS[64 * SSTR];   // 33792 B
  __shared__ float lM[64];
  __shared__ float lL[64];
  __shared__ float lA[64];
  __shared__ int lVL[BB];

  const int tid = (int)threadIdx.x;
  const int w = tid >> 6;    // wave 0..3
  const int l = tid & 63;    // lane
  const int qt = (int)blockIdx.x;   // q-tile (128)
  const int bg = (int)blockIdx.y;   // batch group (4)

  // ---- stage Q into LDS: combo c = b_loc*8 + q_loc ----
  {
    const int c = tid >> 2;
    const int dc = (tid & 3) << 4;
    const int b_g = bg * BB + (c >> 3);
    const int q_g = qt * BQ + (c & 7);
    const float* src = Qg + ((size_t)b_g * TQn + q_g) * Dn + dc;
    float* dst = lQ + c * QSTR + dc;
#pragma unroll
    for (int i = 0; i < 4; ++i)
      *(float4*)(dst + 4 * i) = *(const float4*)(src + 4 * i);
  }
  if (tid < 64) { lM[tid] = -3.0e38f; lL[tid] = 0.0f; }
  if (tid < BB) lVL[tid] = VLg[bg * BB + tid];
  __syncthreads();

  int vmax8 = 0;
#pragma unroll
  for (int i = 0; i < BB; ++i) vmax8 = max(vmax8, lVL[i]);
  const int vl_lane = lVL[l >> 3];                     // phase-1 (combo = lane)
  const int vmax2 = max(lVL[2 * w], lVL[2 * w + 1]);   // phase-2 batch pair

  // phase-1 bases (combo = lane)
  const int b_g1 = bg * BB + (l >> 3);
  const int q_g1 = qt * BQ + (l & 7);
  const float* Kbase = Kg + (size_t)b_g1 * TKn * Dn;
  const float* PKbase = PKg + (size_t)q_g1 * TKn * Dn;
  const float* Qrow = lQ + l * QSTR;

  // phase-2 bases (lane = d, wave handles batches 2w, 2w+1)
  const float* Vb0 = Vg + (size_t)(bg * BB + 2 * w) * TKn * Dn + l;
  const float* Vb1 = Vg + (size_t)(bg * BB + 2 * w + 1) * TKn * Dn + l;
  const float* PVp[8];
#pragma unroll
  for (int q = 0; q < 8; ++q)
    PVp[q] = PVg + (size_t)(qt * BQ + q) * TKn * Dn + l;

  float Oacc[2][8];
#pragma unroll
  for (int b2 = 0; b2 < 2; ++b2)
#pragma unroll
    for (int q = 0; q < 8; ++q) Oacc[b2][q] = 0.0f;

  for (int t = 0; t < NT; ++t) {
    const int k0 = t * KT;
    if (k0 >= vmax8) break;   // uniform across block

    // ---- phase 1: scores for this k-tile ----
#pragma unroll 1
    for (int p = 0; p < KT / 4; ++p) {
      const int kk = 4 * p + w;
      const int kg = k0 + kk;
      float sx = 0.f, sy = 0.f, sz = 0.f, sw = 0.f;
      if (kg < vl_lane) {
        const float* Kr = Kbase + (size_t)kg * Dn;
        const float* PKr = PKbase + (size_t)kg * Dn;
#pragma unroll
        for (int j = 0; j < 16; ++j) {
          const float4 qv = *(const float4*)(Qrow + 4 * j);
          const float4 kv = *(const float4*)(Kr + 4 * j);
          const float4 pv = *(const float4*)(PKr + 4 * j);
          sx += qv.x * (kv.x + pv.x);
          sy += qv.y * (kv.y + pv.y);
          sz += qv.z * (kv.z + pv.z);
          sw += qv.w * (kv.w + pv.w);
        }
      }
      float s = ((sx + sy) + (sz + sw)) * 0.125f;
      if (kg >= vl_lane) s = -1.0e6f;   // mask AFTER scale, like reference
      lS[l * SSTR + kk] = s;
    }
    __syncthreads();

    // ---- online softmax update (4 threads per combo row) ----
    {
      const int c = tid >> 2;
      const int j4 = tid & 3;
      float* row = lS + c * SSTR + j4 * 32;
      float4 sv[8];
      float mloc = -3.0e38f;
#pragma unroll
      for (int i = 0; i < 8; ++i) {
        sv[i] = *(const float4*)(row + 4 * i);
        mloc = fmaxf(mloc, fmaxf(fmaxf(sv[i].x, sv[i].y), fmaxf(sv[i].z, sv[i].w)));
      }
      mloc = fmaxf(mloc, __shfl_xor(mloc, 1));
      mloc = fmaxf(mloc, __shfl_xor(mloc, 2));
      const float m_old = lM[c];
      const float m_new = fmaxf(m_old, mloc);
      float psum = 0.f;
#pragma unroll
      for (int i = 0; i < 8; ++i) {
        float4 pv;
        pv.x = __expf(sv[i].x - m_new);
        pv.y = __expf(sv[i].y - m_new);
        pv.z = __expf(sv[i].z - m_new);
        pv.w = __expf(sv[i].w - m_new);
        psum += (pv.x + pv.y) + (pv.z + pv.w);
        *(float4*)(row + 4 * i) = pv;
      }
      psum += __shfl_xor(psum, 1);
      psum += __shfl_xor(psum, 2);
      if (j4 == 0) {
        const float alpha = __expf(m_old - m_new);
        lM[c] = m_new;
        lL[c] = lL[c] * alpha + psum;
        lA[c] = alpha;
      }
    }
    __syncthreads();

    // ---- phase 2: O += P * (V + pos_v) ----
    {
#pragma unroll
      for (int b2 = 0; b2 < 2; ++b2)
#pragma unroll
        for (int q = 0; q < 8; ++q)
          Oacc[b2][q] *= lA[(2 * w + b2) * 8 + q];

#pragma unroll 1
      for (int kk = 0; kk < KT; kk += 4) {
        if (k0 + kk >= vmax2) break;   // uniform per wave
        float p0[8][4], p1[8][4];
#pragma unroll
        for (int q = 0; q < 8; ++q)
          *(float4*)p0[q] = *(const float4*)(lS + ((2 * w) * 8 + q) * SSTR + kk);
#pragma unroll
        for (int q = 0; q < 8; ++q)
          *(float4*)p1[q] = *(const float4*)(lS + ((2 * w + 1) * 8 + q) * SSTR + kk);
#pragma unroll
        for (int i = 0; i < 4; ++i) {
          const size_t off = (size_t)(k0 + kk + i) * Dn;
          const float v0 = Vb0[off];
          const float v1 = Vb1[off];
#pragma unroll
          for (int q = 0; q < 8; ++q) {
            const float pvv = PVp[q][off];
            Oacc[0][q] += p0[q][i] * (v0 + pvv);
            Oacc[1][q] += p1[q][i] * (v1 + pvv);
          }
        }
      }
    }
    __syncthreads();
  }

  // ---- epilogue: normalize and store (coalesced over d=lane) ----
#pragma unroll
  for (int b2 = 0; b2 < 2; ++b2) {
    const int b_g = bg * BB + 2 * w + b2;
#pragma unroll
    for (int q = 0; q < 8; ++q) {
      const int c = (2 * w + b2) * 8 + q;
      const float inv = 1.0f / lL[c];
      Og[((size_t)b_g * TQn + (size_t)(qt * BQ + q)) * Dn + l] = Oacc[b2][q] * inv;
    }
  }
}

extern "C" void kernel_launch(void* const* d_in, const int* in_sizes, int n_in,
                              void* d_out, int out_size, void* d_ws, size_t ws_size,
                              hipStream_t stream) {
  (void)in_sizes; (void)n_in; (void)out_size; (void)d_ws; (void)ws_size;
  const float* Qg  = (const float*)d_in[0];
  const float* Kg  = (const float*)d_in[1];
  const float* Vg  = (const float*)d_in[2];
  const float* PKg = (const float*)d_in[3];
  const float* PVg = (const float*)d_in[4];
  const int*   VLg = (const int*)d_in[5];
  float* Og = (float*)d_out;

  dim3 grid(TQn / BQ, 32 / BB, 1);   // 128 x 4 = 512 blocks (2/CU)
  dim3 block(256, 1, 1);
  hipLaunchKernelGGL(attn_rpr, grid, block, 0, stream, Qg, Kg, Vg, PKg, PVg, VLg, Og);
}